// Round 1
// baseline (38.656 us; speedup 1.0000x reference)
//
#include <hip/hip_runtime.h>

// DiceLoss: pred [3,1,192,192,192] f32, target same, weight [3] f32 -> scalar f32
// loss = (1/B) * sum_b [ 1 - (2*sum(p*t)*w + 1) / ((sum(p)+sum(t))*w + 1) ],
// p = sigmoid(pred).

constexpr int B_BATCH  = 3;
constexpr int D3       = 192 * 192 * 192;   // 7,077,888 (divisible by 4)
constexpr int N4       = D3 / 4;            // 1,769,472 float4 per batch
constexpr int BLOCKS_X = 682;               // 682*3 = 2046 blocks ~ 8/CU
constexpr int BLK      = 256;

__global__ __launch_bounds__(BLK) void dice_partial(
    const float* __restrict__ pred,
    const float* __restrict__ target,
    float* __restrict__ part /* [B][BLOCKS_X][3] */)
{
    const int b = blockIdx.y;
    const float4* __restrict__ p4 =
        reinterpret_cast<const float4*>(pred) + (size_t)b * N4;
    const float4* __restrict__ t4 =
        reinterpret_cast<const float4*>(target) + (size_t)b * N4;

    float sp = 0.f, st = 0.f, spt = 0.f;
    for (int i = blockIdx.x * BLK + threadIdx.x; i < N4; i += BLOCKS_X * BLK) {
        float4 pv = p4[i];
        float4 tv = t4[i];
        float s0 = 1.f / (1.f + __expf(-pv.x));
        float s1 = 1.f / (1.f + __expf(-pv.y));
        float s2 = 1.f / (1.f + __expf(-pv.z));
        float s3 = 1.f / (1.f + __expf(-pv.w));
        sp  += (s0 + s1) + (s2 + s3);
        st  += (tv.x + tv.y) + (tv.z + tv.w);
        spt += (s0 * tv.x + s1 * tv.y) + (s2 * tv.z + s3 * tv.w);
    }

    // wave64 butterfly reduce
    #pragma unroll
    for (int off = 32; off > 0; off >>= 1) {
        sp  += __shfl_down(sp,  off);
        st  += __shfl_down(st,  off);
        spt += __shfl_down(spt, off);
    }

    __shared__ float red[4][3];
    const int wave = threadIdx.x >> 6;
    const int lane = threadIdx.x & 63;
    if (lane == 0) {
        red[wave][0] = sp;
        red[wave][1] = st;
        red[wave][2] = spt;
    }
    __syncthreads();
    if (threadIdx.x == 0) {
        float a0 = (red[0][0] + red[1][0]) + (red[2][0] + red[3][0]);
        float a1 = (red[0][1] + red[1][1]) + (red[2][1] + red[3][1]);
        float a2 = (red[0][2] + red[1][2]) + (red[2][2] + red[3][2]);
        float* o = part + ((size_t)b * BLOCKS_X + blockIdx.x) * 3;
        o[0] = a0;  // sum p
        o[1] = a1;  // sum t
        o[2] = a2;  // sum p*t
    }
}

// One block, 9 waves: wave w reduces counter (b = w/3, c = w%3) over BLOCKS_X
// partials, then thread 0 computes the scalar loss.
__global__ __launch_bounds__(576) void dice_final(
    const float* __restrict__ part /* [B][BLOCKS_X][3] */,
    const float* __restrict__ weight,
    float* __restrict__ out)
{
    __shared__ float sums[9];  // [b*3 + c]
    const int w    = threadIdx.x >> 6;   // 0..8
    const int lane = threadIdx.x & 63;
    const int b = w / 3;
    const int c = w % 3;

    float s = 0.f;
    for (int i = lane; i < BLOCKS_X; i += 64)
        s += part[((size_t)b * BLOCKS_X + i) * 3 + c];
    #pragma unroll
    for (int off = 32; off > 0; off >>= 1)
        s += __shfl_down(s, off);
    if (lane == 0) sums[w] = s;
    __syncthreads();

    if (threadIdx.x == 0) {
        float loss = 0.f;
        #pragma unroll
        for (int bb = 0; bb < B_BATCH; ++bb) {
            float wgt = weight[bb];
            float sp  = sums[bb * 3 + 0];
            float stv = sums[bb * 3 + 1];
            float spt = sums[bb * 3 + 2];
            float dice = (2.f * spt * wgt + 1.f) / ((sp + stv) * wgt + 1.f);
            loss += 1.f - dice;
        }
        out[0] = loss / (float)B_BATCH;
    }
}

extern "C" void kernel_launch(void* const* d_in, const int* in_sizes, int n_in,
                              void* d_out, int out_size, void* d_ws, size_t ws_size,
                              hipStream_t stream) {
    const float* pred   = (const float*)d_in[0];
    const float* target = (const float*)d_in[1];
    const float* weight = (const float*)d_in[2];
    float* out  = (float*)d_out;
    float* part = (float*)d_ws;  // needs B*BLOCKS_X*3*4 = 24,552 bytes

    dim3 grid(BLOCKS_X, B_BATCH);
    dice_partial<<<grid, BLK, 0, stream>>>(pred, target, part);
    dice_final<<<1, 576, 0, stream>>>(part, weight, out);
}

// Round 2
// 31.744 us; speedup vs baseline: 1.2178x; 1.2178x over previous
//
#include <hip/hip_runtime.h>

// DiceLoss: pred [3,1,192,192,192] f32, target same, weight [3] f32 -> scalar f32
// loss = (1/B) * sum_b [ 1 - (2*sum(p*t)*w + 1) / ((sum(p)+sum(t))*w + 1) ],
// p = sigmoid(pred).

constexpr int B_BATCH  = 3;
constexpr int D3       = 192 * 192 * 192;   // 7,077,888
constexpr int N4       = D3 / 4;            // 1,769,472 float4 per batch
constexpr int BLK      = 256;
constexpr int ITERS    = 12;                // exact: 256*12*576 == N4
constexpr int BLOCKS_X = N4 / (BLK * ITERS); // 576 -> 1728 blocks, all co-resident

__device__ __forceinline__ float fsigmoid(float x) {
    // 1/(1+e^-x) with v_rcp_f32 (~1 ulp) -- plenty for 1e-2 absmax threshold
    return __builtin_amdgcn_rcpf(1.f + __expf(-x));
}

__global__ __launch_bounds__(BLK) void dice_partial(
    const float* __restrict__ pred,
    const float* __restrict__ target,
    float* __restrict__ part /* [B][BLOCKS_X][3] */)
{
    const int b = blockIdx.y;
    const float4* __restrict__ p4 =
        reinterpret_cast<const float4*>(pred) + (size_t)b * N4;
    const float4* __restrict__ t4 =
        reinterpret_cast<const float4*>(target) + (size_t)b * N4;

    const int base = blockIdx.x * (BLK * ITERS) + threadIdx.x;

    // 4 independent accumulator sets to break the FMA chain
    float sp[4]  = {0.f, 0.f, 0.f, 0.f};
    float st[4]  = {0.f, 0.f, 0.f, 0.f};
    float spt[4] = {0.f, 0.f, 0.f, 0.f};

    #pragma unroll
    for (int j = 0; j < ITERS; ++j) {
        float4 pv = p4[base + j * BLK];
        float4 tv = t4[base + j * BLK];
        float s0 = fsigmoid(pv.x);
        float s1 = fsigmoid(pv.y);
        float s2 = fsigmoid(pv.z);
        float s3 = fsigmoid(pv.w);
        const int a = j & 3;
        sp[a]  += (s0 + s1) + (s2 + s3);
        st[a]  += (tv.x + tv.y) + (tv.z + tv.w);
        spt[a] += (s0 * tv.x + s1 * tv.y) + (s2 * tv.z + s3 * tv.w);
    }

    float rsp  = (sp[0]  + sp[1])  + (sp[2]  + sp[3]);
    float rst  = (st[0]  + st[1])  + (st[2]  + st[3]);
    float rspt = (spt[0] + spt[1]) + (spt[2] + spt[3]);

    // wave64 butterfly reduce
    #pragma unroll
    for (int off = 32; off > 0; off >>= 1) {
        rsp  += __shfl_down(rsp,  off);
        rst  += __shfl_down(rst,  off);
        rspt += __shfl_down(rspt, off);
    }

    __shared__ float red[4][3];
    const int wave = threadIdx.x >> 6;
    const int lane = threadIdx.x & 63;
    if (lane == 0) {
        red[wave][0] = rsp;
        red[wave][1] = rst;
        red[wave][2] = rspt;
    }
    __syncthreads();
    if (threadIdx.x == 0) {
        float a0 = (red[0][0] + red[1][0]) + (red[2][0] + red[3][0]);
        float a1 = (red[0][1] + red[1][1]) + (red[2][1] + red[3][1]);
        float a2 = (red[0][2] + red[1][2]) + (red[2][2] + red[3][2]);
        float* o = part + ((size_t)b * BLOCKS_X + blockIdx.x) * 3;
        o[0] = a0;  // sum p
        o[1] = a1;  // sum t
        o[2] = a2;  // sum p*t
    }
}

// One block, 9 waves: wave w reduces counter (b = w/3, c = w%3) over BLOCKS_X
// partials, then thread 0 computes the scalar loss.
__global__ __launch_bounds__(576) void dice_final(
    const float* __restrict__ part /* [B][BLOCKS_X][3] */,
    const float* __restrict__ weight,
    float* __restrict__ out)
{
    __shared__ float sums[9];  // [b*3 + c]
    const int w    = threadIdx.x >> 6;   // 0..8
    const int lane = threadIdx.x & 63;
    const int b = w / 3;
    const int c = w % 3;

    float s = 0.f;
    #pragma unroll
    for (int i = 0; i < BLOCKS_X / 64; ++i)
        s += part[((size_t)b * BLOCKS_X + i * 64 + lane) * 3 + c];
    #pragma unroll
    for (int off = 32; off > 0; off >>= 1)
        s += __shfl_down(s, off);
    if (lane == 0) sums[w] = s;
    __syncthreads();

    if (threadIdx.x == 0) {
        float loss = 0.f;
        #pragma unroll
        for (int bb = 0; bb < B_BATCH; ++bb) {
            float wgt = weight[bb];
            float sp  = sums[bb * 3 + 0];
            float stv = sums[bb * 3 + 1];
            float spt = sums[bb * 3 + 2];
            float dice = (2.f * spt * wgt + 1.f) / ((sp + stv) * wgt + 1.f);
            loss += 1.f - dice;
        }
        out[0] = loss / (float)B_BATCH;
    }
}

extern "C" void kernel_launch(void* const* d_in, const int* in_sizes, int n_in,
                              void* d_out, int out_size, void* d_ws, size_t ws_size,
                              hipStream_t stream) {
    const float* pred   = (const float*)d_in[0];
    const float* target = (const float*)d_in[1];
    const float* weight = (const float*)d_in[2];
    float* out  = (float*)d_out;
    float* part = (float*)d_ws;  // needs B*BLOCKS_X*3*4 = 20,736 bytes

    dim3 grid(BLOCKS_X, B_BATCH);
    dice_partial<<<grid, BLK, 0, stream>>>(pred, target, part);
    dice_final<<<1, 576, 0, stream>>>(part, weight, out);
}